// Round 10
// baseline (377.692 us; speedup 1.0000x reference)
//
#include <hip/hip_runtime.h>
#include <hip/hip_bf16.h>

typedef __hip_bfloat16 bf16;

#define NH   16
#define HD   128
#define SEQ  2048
#define BB   2
#define HID  2048

// ln(10000)/64
#define ROPE_C 0.14391156856f

using frag   = __attribute__((ext_vector_type(8))) short;   // 8 bf16 = 4 VGPRs
using f32x4  = __attribute__((ext_vector_type(4))) float;
using f32x16 = __attribute__((ext_vector_type(16))) float;

// ---------- helpers ----------

// pack 8 fp32 -> 8 bf16 (one 16B LDS write)
__device__ __forceinline__ void cvt8_store(const float4 f0, const float4 f1, bf16* dst) {
    union { frag v; bf16 h[8]; } p;
    p.h[0] = __float2bfloat16(f0.x); p.h[1] = __float2bfloat16(f0.y);
    p.h[2] = __float2bfloat16(f0.z); p.h[3] = __float2bfloat16(f0.w);
    p.h[4] = __float2bfloat16(f1.x); p.h[5] = __float2bfloat16(f1.y);
    p.h[6] = __float2bfloat16(f1.z); p.h[7] = __float2bfloat16(f1.w);
    *reinterpret_cast<frag*>(dst) = p.v;
}

// pack 2 fp32 -> 1 dword of 2 bf16
__device__ __forceinline__ unsigned pk2(float a, float b) {
    union { bf16 h[2]; unsigned u; } p;
    p.h[0] = __float2bfloat16(a);
    p.h[1] = __float2bfloat16(b);
    return p.u;
}

// async global->LDS, 16B per lane (dest = wave-uniform base + lane*16)
__device__ __forceinline__ void gld_lds16(const bf16* g, bf16* l) {
    __builtin_amdgcn_global_load_lds(
        (const __attribute__((address_space(1))) void*)g,
        (__attribute__((address_space(3))) void*)l, 16, 0, 0);
}

// ---------- prepass: fp32 -> bf16 for hs, Wq, Wk, Wv ----------
__global__ __launch_bounds__(256) void cvt_bf16(const float* __restrict__ hs,
                                                const float* __restrict__ Wq,
                                                const float* __restrict__ Wk,
                                                const float* __restrict__ Wv,
                                                bf16* __restrict__ hsb,
                                                bf16* __restrict__ wqb,
                                                bf16* __restrict__ wkb,
                                                bf16* __restrict__ wvb) {
    const int blk = blockIdx.x;
    const float* src;
    bf16* dst;
    if (blk < 4096)      { src = hs + (size_t)blk * 2048;          dst = hsb + (size_t)blk * 2048; }
    else if (blk < 6144) { src = Wq + (size_t)(blk - 4096) * 2048; dst = wqb + (size_t)(blk - 4096) * 2048; }
    else if (blk < 6272) { src = Wk + (size_t)(blk - 6144) * 2048; dst = wkb + (size_t)(blk - 6144) * 2048; }
    else                 { src = Wv + (size_t)(blk - 6272) * 2048; dst = wvb + (size_t)(blk - 6272) * 2048; }
    const int t = threadIdx.x * 8;
    const float4 f0 = *reinterpret_cast<const float4*>(src + t);
    const float4 f1 = *reinterpret_cast<const float4*>(src + t + 4);
    cvt8_store(f0, f1, dst + t);
}

// ---------- fused Q/K/V projection: 4-wave 128x128 tiles, 64x64/wave, 2-phase dbuf ----------
// Round-10: double-buffered LDS; next K-step's global_load_lds issued BEFORE the
// current step's ds_read+MFMA, single barrier per step. Stage latency hides
// under compute (we have only ~9 waves/CU at this grid, so block-level overlap
// is weak -- unlike m99/m100's 12-wave case where dbuf was neutral).
__global__ __launch_bounds__(256, 4) void gemm_qkv(const bf16* __restrict__ A,
                                                   const bf16* __restrict__ Wqb,
                                                   const bf16* __restrict__ Wkb,
                                                   const bf16* __restrict__ Wvb,
                                                   bf16* __restrict__ qout,
                                                   float* __restrict__ Ck,
                                                   float* __restrict__ Cv,
                                                   bf16* __restrict__ kb,
                                                   bf16* __restrict__ vt) {
    __shared__ bf16 Asl[2][4096];   // 128 rows x 32 k, chunk n at byte n*16
    __shared__ bf16 Bsl[2][4096];
    const int tid  = threadIdx.x;
    const int wave = tid >> 6;
    const int lane = tid & 63;
    const int quad = lane >> 4;
    const int l15  = lane & 15;
    const int wr   = wave >> 1;       // 0..1 row-group
    const int wc   = wave & 1;        // 0..1 col-group
    const int row0 = blockIdx.y * 128;
    const int bx   = blockIdx.x;
    const bool isq  = bx < 16;
    const bool is_v = (bx == 17);
    const bf16* W   = isq ? Wqb : (is_v ? Wvb : Wkb);
    const int col0  = isq ? bx * 128 : 0;

    const int sr = tid >> 2;          // 0..63
    const int sc = (tid & 3) * 8;     // 0,8,16,24
    const int sg = ((sr >> 5) & 1) * 64 + (sr & 31);   // sigma(sr), sr<64

    const bf16* ag = A + (size_t)(row0 + sr) * HID + sc;
    const bf16* bg = W + (size_t)(col0 + sg) * HID + sc;

    f32x4 acc[4][4];
#pragma unroll
    for (int i = 0; i < 4; ++i)
#pragma unroll
        for (int j = 0; j < 4; ++j) acc[i][j] = (f32x4){0.f,0.f,0.f,0.f};

    // prologue: stage K-step 0 into buf 0
    gld_lds16(ag,                      &Asl[0][tid * 8]);
    gld_lds16(ag + (size_t)64 * HID,   &Asl[0][tid * 8 + 2048]);
    gld_lds16(bg,                      &Bsl[0][tid * 8]);
    gld_lds16(bg + (size_t)32 * HID,   &Bsl[0][tid * 8 + 2048]);
    __syncthreads();

    for (int t = 0; t < 64; ++t) {
        const int cur = t & 1;
        if (t < 63) {
            const int kn = (t + 1) * 32;
            gld_lds16(ag + kn,                    &Asl[cur ^ 1][tid * 8]);
            gld_lds16(ag + (size_t)64 * HID + kn, &Asl[cur ^ 1][tid * 8 + 2048]);
            gld_lds16(bg + kn,                    &Bsl[cur ^ 1][tid * 8]);
            gld_lds16(bg + (size_t)32 * HID + kn, &Bsl[cur ^ 1][tid * 8 + 2048]);
        }
        frag af[4], bfr[4];
#pragma unroll
        for (int i = 0; i < 4; ++i)
            af[i] = *reinterpret_cast<const frag*>(&Asl[cur][(((wr*64 + i*16 + l15)*4) + quad) * 8]);
#pragma unroll
        for (int j = 0; j < 4; ++j)
            bfr[j] = *reinterpret_cast<const frag*>(&Bsl[cur][(((wc*64 + j*16 + l15)*4) + quad) * 8]);
#pragma unroll
        for (int i = 0; i < 4; ++i)
#pragma unroll
            for (int j = 0; j < 4; ++j)
                acc[i][j] = __builtin_amdgcn_mfma_f32_16x16x32_bf16(af[i], bfr[j], acc[i][j], 0, 0, 0);
        __syncthreads();   // drains in-flight stage -> buf^1 ready
    }

    // wave covers cols {wc*32 + [0,32)} and {+64} (sigma pairing)
    if (isq) {
#pragma unroll
        for (int i = 0; i < 4; ++i)
#pragma unroll
            for (int r = 0; r < 4; ++r) {
                const int row = row0 + wr*64 + i*16 + quad*4 + r;
                const int s = row & (SEQ - 1);
                bf16* crow = qout + (size_t)row * HID + col0;
#pragma unroll
                for (int j = 0; j < 2; ++j) {
                    const int d = wc*32 + 16*j + l15;
                    const float invf = expf(-(float)d * ROPE_C);
                    float sn, cs;
                    sincosf((float)s * invf, &sn, &cs);
                    const float x1 = acc[i][j][r], x2 = acc[i][j+2][r];
                    crow[d]      = __float2bfloat16(x1*cs - x2*sn);
                    crow[d + 64] = __float2bfloat16(x2*cs + x1*sn);
                }
            }
    } else if (is_v) {
#pragma unroll
        for (int i = 0; i < 4; ++i)
#pragma unroll
            for (int r = 0; r < 4; ++r) {
                const int row = row0 + wr*64 + i*16 + quad*4 + r;   // b*SEQ + s
                const int s = row & (SEQ - 1);
                const int b = row >> 11;
                float* crow = Cv + (size_t)row * HD;
#pragma unroll
                for (int j = 0; j < 4; ++j) {
                    const int d = (j >> 1)*64 + wc*32 + (j & 1)*16 + l15;
                    const float val = acc[i][j][r];
                    crow[d] = val;
                    vt[((size_t)b * HD + d) * SEQ + s] = __float2bfloat16(val);
                }
            }
    } else {
#pragma unroll
        for (int i = 0; i < 4; ++i)
#pragma unroll
            for (int r = 0; r < 4; ++r) {
                const int row = row0 + wr*64 + i*16 + quad*4 + r;
                const int s = row & (SEQ - 1);
                float* crow = Ck + (size_t)row * HD;
#pragma unroll
                for (int j = 0; j < 2; ++j) {
                    const int d = wc*32 + 16*j + l15;
                    const float invf = expf(-(float)d * ROPE_C);
                    float sn, cs;
                    sincosf((float)s * invf, &sn, &cs);
                    const float y1 = acc[i][j][r]*cs - acc[i][j+2][r]*sn;
                    const float y2 = acc[i][j+2][r]*cs + acc[i][j][r]*sn;
                    crow[d]      = y1;
                    crow[d + 64] = y2;
                    kb[(size_t)row * HD + d]      = __float2bfloat16(y1);
                    kb[(size_t)row * HD + d + 64] = __float2bfloat16(y2);
                }
            }
    }
}

// ---------- flash MFMA attention, 32x32x16, 4-wave key-split blocks ----------
// Round-10 change: V staging rebuilt as 16B chunks mirroring K's layout exactly
// (two 8B global granules gathered into one uint4, single b128 LDS write).
// Same LDS bytes as before (verified element-level) -> read path unchanged.
// Phase analysis: all LDS writes now <=2-way bank-aliased (free, m136);
// was 4-way on the 8B V granules (1.678e7 conflict cycles = 21% of wall).
__global__ __launch_bounds__(256) void attn_mfma(const bf16* __restrict__ qbuf,
                                                 const bf16* __restrict__ kb,
                                                 const bf16* __restrict__ vt,
                                                 bf16* __restrict__ attn_out) {
    __shared__ char lds[32768];

    const int tid  = threadIdx.x;
    const int wave = tid >> 6;
    const int lane = tid & 63;
    const int l31  = lane & 31;
    const int h    = lane >> 5;
    const int qg   = wave & 1;
    const int kg   = wave >> 1;
    const int q0   = blockIdx.x * 64;
    const int hh   = blockIdx.y;      // head
    const int b    = blockIdx.z;

    const bf16* kbb = kb + (size_t)b * SEQ * HD;
    const bf16* vtb = vt + (size_t)b * HD * SEQ;

    // Q B-frags: qfr[c] = Q[qrow = q0+qg*32+l31][dims c*16 + h*8 .. +7]
    frag qfr[8];
    {
        const bf16* qrow = qbuf + ((size_t)(b * SEQ + q0 + qg * 32 + l31)) * HID + hh * HD;
#pragma unroll
        for (int c = 0; c < 8; ++c)
            qfr[c] = *reinterpret_cast<const frag*>(qrow + c * 16 + h * 8);
    }

    // staging: 128 threads (sl) per kg_s half
    const int sl   = tid & 127;
    const int kg_s = tid >> 7;

    // K: 4 x 16B chunks, global-contiguous n = sl + i*128 (global elem = 8n)
    //    n -> key=n>>4, d=(n>>1)&7, hs=n&1 ; LDS L = d*64 + key*2 + hs
    int klof[4];
#pragma unroll
    for (int i = 0; i < 4; ++i) {
        const int n   = sl + i * 128;
        const int key = n >> 4, d = (n >> 1) & 7, hs = n & 1;
        const int L   = d * 64 + key * 2 + hs;
        klof[i] = (kg_s * 8192 + L * 16) ^ (((((key >> 2) ^ d) & 7)) << 4);
    }
    // V: 4 x 16B chunks q = sl + i*128, mirror of K's LDS shape:
    // chunk cb = q>>6 (dt=cb>>1, ks=cb&1), slot s = q&63 (dim&31 = s>>1, hs=s&1)
    // byte = 16384 + kg_s*8192 + (q*16 ^ ((((q>>3)&7) ^ cb)<<4))
    // data = V^T[dim][keys (ks*4+hs)*4 .. +3 and +8 .. +11] (two 8B granules)
    int vlof[4], vgof[4];
#pragma unroll
    for (int i = 0; i < 4; ++i) {
        const int q  = sl + i * 128;
        const int cb = q >> 6;
        const int dim = ((q >> 7) << 5) + ((q >> 1) & 31);
        const int ks  = cb & 1, hs = q & 1;
        vlof[i] = 16384 + kg_s * 8192 + ((q * 16) ^ (((((q >> 3) & 7) ^ cb)) << 4));
        vgof[i] = dim * SEQ + kg_s * 32 + (ks * 4 + hs) * 4;
    }

    // frag-read base: within-chunk byte (l31*2+h)*16, swizzled (>>7 term);
    // per-chunk (>>10) term applied as compile-time (cb<<4) XOR at use site.
    const int rpos = (l31 * 2 + h) * 16;
    const int rsw  = rpos ^ ((((rpos >> 7) & 7)) << 4);

    f32x16 oacc[4];
#pragma unroll
    for (int dt = 0; dt < 4; ++dt)
#pragma unroll
        for (int r = 0; r < 16; ++r) oacc[dt][r] = 0.f;
    float mrow = -1e30f;
    float lrow = 0.f;
    const float scale = 0.088388347648318433f;   // 1/sqrt(128)

    for (int it = 0; it < SEQ / 64; ++it) {
        __syncthreads();
        {
            const bf16* kp = kbb + (size_t)it * 64 * HD + kg_s * 4096;
            const bf16* vp = vtb + it * 64;
            uint4 krg[4];
            uint4 vrg[4];
#pragma unroll
            for (int i = 0; i < 4; ++i)
                krg[i] = *reinterpret_cast<const uint4*>(kp + (sl + i * 128) * 8);
#pragma unroll
            for (int i = 0; i < 4; ++i) {
                const uint2 a = *reinterpret_cast<const uint2*>(vp + vgof[i]);
                const uint2 c = *reinterpret_cast<const uint2*>(vp + vgof[i] + 8);
                vrg[i] = (uint4){a.x, a.y, c.x, c.y};
            }
#pragma unroll
            for (int i = 0; i < 4; ++i)
                *reinterpret_cast<uint4*>(lds + klof[i]) = krg[i];
#pragma unroll
            for (int i = 0; i < 4; ++i)
                *reinterpret_cast<uint4*>(lds + vlof[i]) = vrg[i];
        }
        __syncthreads();

        // S^T (32 keys x 32 qrows): rows = keys (r&3)+8*(r>>2)+4h, col = l31
        f32x16 sacc;
#pragma unroll
        for (int r = 0; r < 16; ++r) sacc[r] = 0.f;
#pragma unroll
        for (int c = 0; c < 8; ++c) {
            const frag kf = *reinterpret_cast<const frag*>(
                lds + kg * 8192 + c * 1024 + (rsw ^ (c << 4)));
            sacc = __builtin_amdgcn_mfma_f32_32x32x16_bf16(kf, qfr[c], sacc, 0, 0, 0);
        }

        // online softmax for qrow = l31 (partner h via xor-32)
        float mx = -1e30f;
#pragma unroll
        for (int r = 0; r < 16; ++r) mx = fmaxf(mx, sacc[r]);
        mx = fmaxf(mx, __shfl_xor(mx, 32));
        const bool skip = (bool)__all(mx - mrow <= 90.0f);   // e^(90*scale) ~ e^8
        const float mn = skip ? mrow : fmaxf(mrow, mx);
        const float al = skip ? 1.f : __expf((mrow - mn) * scale);
        float p[16];
        float ps = 0.f;
#pragma unroll
        for (int r = 0; r < 16; ++r) {
            p[r] = __expf((sacc[r] - mn) * scale);
            ps += p[r];
        }
        ps += __shfl_xor(ps, 32);
        lrow = lrow * al + ps;
        mrow = mn;

        // PV B-frags: pb[ks] elem j = p[8ks+j] (pi-permuted V key order)
        frag pb[2];
#pragma unroll
        for (int ks = 0; ks < 2; ++ks) {
            union { unsigned u[4]; frag f; } pf;
#pragma unroll
            for (int w = 0; w < 4; ++w)
                pf.u[w] = pk2(p[8 * ks + 2 * w], p[8 * ks + 2 * w + 1]);
            pb[ks] = pf.f;
        }

        if (!skip)
#pragma unroll
            for (int dt = 0; dt < 4; ++dt)
#pragma unroll
                for (int r = 0; r < 16; ++r) oacc[dt][r] *= al;

        // O^T += V^T P^T
#pragma unroll
        for (int dt = 0; dt < 4; ++dt)
#pragma unroll
            for (int ks = 0; ks < 2; ++ks) {
                const int cb = dt * 2 + ks;
                const frag vf = *reinterpret_cast<const frag*>(
                    lds + 16384 + kg * 8192 + cb * 1024 + (rsw ^ (cb << 4)));
                oacc[dt] = __builtin_amdgcn_mfma_f32_32x32x16_bf16(vf, pb[ks], oacc[dt], 0, 0, 0);
            }
    }

    // ---- flash-decoding merge across kg pairs ----
    __syncthreads();
    float* fl = reinterpret_cast<float*>(lds);
    if (h == 0) {
        fl[(qg * 2 + kg) * 32 + l31]       = mrow;
        fl[128 + (qg * 2 + kg) * 32 + l31] = lrow;
    }
    __syncthreads();
    const float m0 = fl[qg * 64 + l31],       m1 = fl[qg * 64 + 32 + l31];
    const float l0 = fl[128 + qg * 64 + l31], l1 = fl[128 + qg * 64 + 32 + l31];
    const float ms = fmaxf(m0, m1);
    const float c0 = __expf((m0 - ms) * scale);
    const float c1 = __expf((m1 - ms) * scale);
    const float inv = 1.f / (c0 * l0 + c1 * l1);
    const float cs = kg ? c1 : c0;
#pragma unroll
    for (int dt = 0; dt < 4; ++dt)
#pragma unroll
        for (int r = 0; r < 16; ++r) oacc[dt][r] *= cs;

    float* ob = reinterpret_cast<float*>(lds + 1024);   // [qg*64+lane][17] padded
#pragma unroll
    for (int dt = 0; dt < 4; ++dt) {
        __syncthreads();
        if (kg == 1) {
            float* dst = ob + (qg * 64 + lane) * 17;
#pragma unroll
            for (int r = 0; r < 16; ++r) dst[r] = oacc[dt][r];
        }
        __syncthreads();
        if (kg == 0) {
            const float* sp = ob + (qg * 64 + lane) * 17;
            const int s = q0 + qg * 32 + l31;
            bf16* orow = attn_out + ((size_t)(b * SEQ + s)) * HID + hh * HD;
#pragma unroll
            for (int t = 0; t < 4; ++t) {
                const float v0 = (oacc[dt][t*4+0] + sp[t*4+0]) * inv;
                const float v1 = (oacc[dt][t*4+1] + sp[t*4+1]) * inv;
                const float v2 = (oacc[dt][t*4+2] + sp[t*4+2]) * inv;
                const float v3 = (oacc[dt][t*4+3] + sp[t*4+3]) * inv;
                uint2 val;
                val.x = pk2(v0, v1);
                val.y = pk2(v2, v3);
                *reinterpret_cast<uint2*>(orow + dt * 32 + t * 8 + h * 4) = val;
            }
        }
    }
}

// ---------- final projection: 4-wave 128x128 tiles, 64x64/wave, 2-phase dbuf ----------
// A via global_load_lds; W fp32 via T14 split: loads issued early (overlap MFMA),
// cvt+ds_write late, one barrier per K-step.
__global__ __launch_bounds__(256, 3) void gemm_o_mfma(const bf16* __restrict__ A,
                                                      const float* __restrict__ W,
                                                      float* __restrict__ C) {
    __shared__ bf16 Asl[2][4096];
    __shared__ bf16 Bsl[2][4096];
    const int tid  = threadIdx.x;
    const int wave = tid >> 6;
    const int lane = tid & 63;
    const int quad = lane >> 4;
    const int l15  = lane & 15;
    const int wr   = wave >> 1;
    const int wc   = wave & 1;
    const int row0 = blockIdx.y * 128;
    const int col0 = blockIdx.x * 128;

    const int sr = tid >> 2;          // 0..63
    const int sc = (tid & 3) * 8;

    const bf16* ag = A + (size_t)(row0 + sr) * HID + sc;
    const float* wg0 = W + (size_t)(col0 + sr) * HID + sc;
    const float* wg1 = wg0 + (size_t)64 * HID;

    f32x4 acc[4][4];
#pragma unroll
    for (int i = 0; i < 4; ++i)
#pragma unroll
        for (int j = 0; j < 4; ++j) acc[i][j] = (f32x4){0.f,0.f,0.f,0.f};

    // prologue: stage K-step 0 into buf 0
    gld_lds16(ag,                    &Asl[0][tid * 8]);
    gld_lds16(ag + (size_t)64 * HID, &Asl[0][tid * 8 + 2048]);
    {
        const float4 b0 = *reinterpret_cast<const float4*>(wg0);
        const float4 b1 = *reinterpret_cast<const float4*>(wg0 + 4);
        const float4 b2 = *reinterpret_cast<const float4*>(wg1);
        const float4 b3 = *reinterpret_cast<const float4*>(wg1 + 4);
        cvt8_store(b0, b1, &Bsl[0][tid * 8]);
        cvt8_store(b2, b3, &Bsl[0][tid * 8 + 2048]);
    }
    __syncthreads();

    for (int t = 0; t < 64; ++t) {
        const int cur = t & 1;
        float4 nb0, nb1, nb2, nb3;
        if (t < 63) {
            const int kn = (t + 1) * 32;
            gld_lds16(ag + kn,                    &Asl[cur ^ 1][tid * 8]);
            gld_lds16(ag + (size_t)64 * HID + kn, &Asl[cur ^ 1][tid * 8 + 2048]);
            nb0 = *reinterpret_cast<const float4*>(wg0 + kn);
            nb1 = *reinterpret_cast<const float4*>(wg0 + kn + 4);
            nb2 = *reinterpret_cast<const float4*>(wg1 + kn);
            nb3 = *reinterpret_cast<const float4*>(wg1 + kn + 4);
        }
        frag af[4], bfr[4];
#pragma unroll
        for (int i = 0; i < 4; ++i)
            af[i] = *reinterpret_cast<const frag*>(&Asl[cur][(((wr*64 + i*16 + l15)*4) + quad) * 8]);
#pragma unroll
        for (int j = 0; j < 4; ++j)
            bfr[j] = *reinterpret_cast<const frag*>(&Bsl[cur][(((wc*64 + j*16 + l15)*4) + quad) * 8]);
#pragma unroll
        for (int i = 0; i < 4; ++i)
#pragma unroll
            for (int j = 0; j < 4; ++j)
                acc[i][j] = __builtin_amdgcn_mfma_f32_16x16x32_bf16(af[i], bfr[j], acc[i][j], 0, 0, 0);
        if (t < 63) {
            cvt8_store(nb0, nb1, &Bsl[cur ^ 1][tid * 8]);
            cvt8_store(nb2, nb3, &Bsl[cur ^ 1][tid * 8 + 2048]);
        }
        __syncthreads();
    }

#pragma unroll
    for (int i = 0; i < 4; ++i)
#pragma unroll
        for (int r = 0; r < 4; ++r) {
            const int row = row0 + wr*64 + i*16 + quad*4 + r;
            float* crow = C + (size_t)row * HID + col0 + wc*64;
#pragma unroll
            for (int j = 0; j < 4; ++j)
                crow[16*j + l15] = acc[i][j][r];
        }
}

// ---------- launch ----------
extern "C" void kernel_launch(void* const* d_in, const int* in_sizes, int n_in,
                              void* d_out, int out_size, void* d_ws, size_t ws_size,
                              hipStream_t stream) {
    const float* hs = (const float*)d_in[0];
    const float* Wq = (const float*)d_in[1];
    const float* Wk = (const float*)d_in[2];
    const float* Wv = (const float*)d_in[3];
    const float* Wo = (const float*)d_in[4];

    float* out      = (float*)d_out;
    float* out_attn = out;                         // [B,S,H]    8388608 f32 (33.55 MB)
    float* out_k    = out + 8388608;               // [B,1,S,HD]  524288 f32
    float* out_v    = out + 8388608 + 524288;      // [B,1,S,HD]  524288 f32

    // Scratch in d_out's attn region (all consumed before gemm_o writes it):
    bf16* qbuf = (bf16*)d_out;                             // [0 .. 16777216)      roped q bf16
    bf16* kb   = (bf16*)((char*)d_out + 16777216);         // [.. 17825792)        roped k bf16
    bf16* vt   = (bf16*)((char*)d_out + 17825792);         // [.. 18874368)        v^T bf16
    bf16* wqb  = (bf16*)((char*)d_out + 18874368);         // [.. 27262976)        Wq bf16
    bf16* wkb  = (bf16*)((char*)d_out + 27262976);         // [.. 27787264)        Wk bf16
    bf16* wvb  = (bf16*)((char*)d_out + 27787264);         // [.. 28311552)        Wv bf16
    // ws[0..16.78M): hs_bf during {cvt,gemm_qkv}; attn_out during {attn,gemm_o}
    bf16* hsb      = (bf16*)d_ws;
    bf16* attn_out = (bf16*)d_ws;

    cvt_bf16  <<<dim3(6400),                  dim3(256), 0, stream>>>(hs, Wq, Wk, Wv, hsb, wqb, wkb, wvb);
    gemm_qkv  <<<dim3(18, (BB*SEQ)/128),      dim3(256), 0, stream>>>(hsb, wqb, wkb, wvb,
                                                                      qbuf, out_k, out_v, kb, vt);
    attn_mfma <<<dim3(SEQ/64, NH, BB),        dim3(256), 0, stream>>>(qbuf, kb, vt, attn_out);
    gemm_o_mfma<<<dim3(HID/128, (BB*SEQ)/128), dim3(256), 0, stream>>>(attn_out, Wo, out_attn);
}